// Round 6
// baseline (183.000 us; speedup 1.0000x reference)
//
#include <hip/hip_runtime.h>
#include <hip/hip_bf16.h>

// B=512, A=4, D=6, N=1365, E=128. Level starts {0,1,5,21,85,341}.
// Round 6: split the latency chain. R5 profile: all pipes idle (Mfma 1%,
// VALU 2.4%, HBM 7%) -> 24-phase serial chain at 2 blocks/CU is latency-
// bound. The tree is hierarchical: quarter q (4 leaf phases + L4 phase)
// is independent -> tree_q grid 2048 (4 blocks/tree, 5 phases, 2 barriers),
// CS3 rows + partial relu-max to workspace; tree_tail grid 512 replays
// phases n=20..23 and merges. Same bf16 values flow -> absmax unchanged.
// No inline asm anywhere (asm => mayUseAGPRs => VGPR budget halved, R2/R3).
// Fallback: if ws too small, run the round-0 verified kernel unchanged.
#define NTOK 1365
#define ED   128
#define STR  136   // bf16 LDS row stride: 272 B, 16B-aligned, balanced banks
#define VROWS 50000
#define PROWS 50048

#define P_BYTES  ((size_t)PROWS * ED * 2)            // 12,812,288
#define G3_OFF   P_BYTES                             // 512*64 rows bf16
#define G3_BYTES ((size_t)512 * 64 * ED * 2)         //  8,388,608
#define GPM_OFF  (G3_OFF + G3_BYTES)                 // 21,200,896
#define GPM_BYTES ((size_t)512 * 4 * ED * 4)         //  1,048,576
#define WS_NEED  (GPM_OFF + GPM_BYTES)               // 22,249,472

typedef __attribute__((ext_vector_type(8))) short short8;
typedef __attribute__((ext_vector_type(4))) float f32x4;

#define MFMA(a,b,c) __builtin_amdgcn_mfma_f32_16x16x32_bf16((a),(b),(c),0,0,0)

// LDS-scoped release/acquire around a raw barrier: lgkmcnt-only wait, global
// gathers stay in flight. Pure intrinsics (no inline asm -> no AGPR split).
#define BAR() do {                                                   \
    __builtin_amdgcn_fence(__ATOMIC_RELEASE, "workgroup", "local");  \
    __builtin_amdgcn_s_barrier();                                    \
    __builtin_amdgcn_fence(__ATOMIC_ACQUIRE, "workgroup", "local");  \
  } while (0)

__device__ __forceinline__ ushort f2bf(float f) {  // round-to-nearest-even
  union { float f; unsigned u; } v; v.f = f;
  unsigned r = v.u + 0x7fffu + ((v.u >> 16) & 1u);
  return (ushort)(r >> 16);
}
__device__ __forceinline__ ushort4 cvt4(float4 f) {
  ushort4 u; u.x = f2bf(f.x); u.y = f2bf(f.y); u.z = f2bf(f.z); u.w = f2bf(f.w);
  return u;
}
__device__ __forceinline__ short8 pack8(float4 a, float4 b) {
  union { ushort us[8]; short8 s8; } t;
  t.us[0]=f2bf(a.x); t.us[1]=f2bf(a.y); t.us[2]=f2bf(a.z); t.us[3]=f2bf(a.w);
  t.us[4]=f2bf(b.x); t.us[5]=f2bf(b.y); t.us[6]=f2bf(b.z); t.us[7]=f2bf(b.w);
  return t.s8;
}

// ---------------------------------------------------------------------------
// proj_kernel: P[v][c] = (emb @ Wc^T)[v][c] + Wcb[c], bf16. (unchanged)
// ---------------------------------------------------------------------------
__global__ __attribute__((amdgpu_flat_work_group_size(256, 256)))
void proj_kernel(const float* __restrict__ emb, const float* __restrict__ WcW,
                 const float* __restrict__ Wcb, ushort* __restrict__ P) {
  __shared__ ushort At[64 * STR];
  const int tid = threadIdx.x, w = tid >> 6, lane = tid & 63;
  const int n16 = lane & 15, quad = lane >> 4, kof = quad * 8;
  const int m0 = blockIdx.x * 64;

  #pragma unroll
  for (int i = 0; i < 8; i++) {
    const int idx = tid + i*256;
    const int r = idx >> 5, c4 = idx & 31;
    int arow = m0 + r; if (arow >= VROWS) arow = 0;      // pad rows safe
    float4 f = ((const float4*)(emb + (long)arow*ED))[c4];
    *(ushort4*)(At + r*STR + (c4 << 2)) = cvt4(f);
  }

  float bv[2];
  short8 Bp[2][4];
  #pragma unroll
  for (int j = 0; j < 2; j++) {
    const int c = w*32 + j*16 + n16;
    bv[j] = Wcb[c];
    #pragma unroll
    for (int kb = 0; kb < 4; kb++) {
      const float* pc = WcW + c*ED + kb*32 + kof;
      Bp[j][kb] = pack8(((const float4*)pc)[0], ((const float4*)pc)[1]);
    }
  }
  __syncthreads();

  #pragma unroll
  for (int i = 0; i < 4; i++) {
    f32x4 acc0 = (f32x4){0.f,0.f,0.f,0.f}, acc1 = (f32x4){0.f,0.f,0.f,0.f};
    #pragma unroll
    for (int kb = 0; kb < 4; kb++) {
      short8 a = *(const short8*)(At + (i*16 + n16)*STR + kb*32 + kof);
      acc0 = MFMA(a, Bp[0][kb], acc0);
      acc1 = MFMA(a, Bp[1][kb], acc1);
    }
    #pragma unroll
    for (int r = 0; r < 4; r++) {
      const int orow = m0 + i*16 + quad*4 + r;   // C layout: row=quad*4+reg
      if (orow < VROWS) {
        P[(long)orow*ED + w*32 + n16]      = f2bf(acc0[r] + bv[0]);
        P[(long)orow*ED + w*32 + 16 + n16] = f2bf(acc1[r] + bv[1]);
      }
    }
  }
}

// ---------------------------------------------------------------------------
// tree_q: one block per (tree, quarter). 4 leaf phases + L4 phase.
// Writes CS3 rows (bf16) to G3 and partial relu-max to GPM.
// ---------------------------------------------------------------------------
__global__ __attribute__((amdgpu_flat_work_group_size(512, 512),
                          amdgpu_waves_per_eu(4, 4)))
void tree_q(const int* __restrict__ tokens, const ushort* __restrict__ P,
            const float* __restrict__ WsW,  const float* __restrict__ Wsb,
            ushort* __restrict__ G3, float* __restrict__ GPM) {
  __shared__ int    TK[320];        // 256 leaf tokens + 64 L4 tokens
  __shared__ ushort CS4[64 * STR];  // leaf child-sums
  __shared__ ushort CS3q[16 * STR]; // this quarter's CS3 rows
  __shared__ float  PM[1024];       // per-wave col maxima (no init needed)

  const int tid = threadIdx.x;
  const int bq  = blockIdx.x, b = bq >> 2, q = bq & 3;
  const int w    = tid >> 6;
  const int lane = tid & 63;
  const int n16  = lane & 15;
  const int quad = lane >> 4;
  const int mtg  = w >> 2, ntg = w & 3;
  const int kof  = quad * 8;

  if (tid < 320) {
    const long tokbase = (long)b * NTOK;
    TK[tid] = (tid < 256) ? tokens[tokbase + 341 + q*256 + tid]
                          : tokens[tokbase + 85 + q*64 + (tid - 256)];
  }

  float bsv[2];
  #pragma unroll
  for (int j = 0; j < 2; j++) bsv[j] = 4.f * Wsb[ntg*32 + j*16 + n16];

  short8 Bs[2][4];
  #pragma unroll
  for (int jt = 0; jt < 2; jt++)
    #pragma unroll
    for (int kb = 0; kb < 4; kb++) {
      const float* pc = WsW + (ntg*32 + jt*16 + n16)*ED + kb*32 + kof;
      Bs[jt][kb] = pack8(((const float4*)pc)[0], ((const float4*)pc)[1]);
    }

  short8 I2[2];
  #pragma unroll
  for (int j = 0; j < 2; j++) {
    union { ushort us[8]; short8 s8; } t;
    #pragma unroll
    for (int e = 0; e < 8; e++) t.us[e] = 0;
    if (quad == 2*j + (n16 >> 3)) t.us[n16 & 7] = 0x3F80;
    I2[j] = t.s8;
  }

  float pm[2] = {0.f, 0.f};

  short8 FA[2], FB[2];
  auto issueF = [&](short8 (&F)[2], int ofs) {
    const int co = ntg*32 + kof;
    F[0] = *(const short8*)(P + (long)TK[ofs + mtg*32      + n16]*ED + co);
    F[1] = *(const short8*)(P + (long)TK[ofs + mtg*32 + 16 + n16]*ED + co);
  };

  auto phase64 = [&](const short8 (&F)[2], const ushort* csrc, ushort* csdst,
                     int csrow0) {
    f32x4 acc[2][2];
    #pragma unroll
    for (int i = 0; i < 2; i++)
      #pragma unroll
      for (int j = 0; j < 2; j++) acc[i][j] = (f32x4){0.f,0.f,0.f,0.f};
    acc[0][0]=MFMA(F[0],I2[0],acc[0][0]); acc[0][1]=MFMA(F[0],I2[1],acc[0][1]);
    acc[1][0]=MFMA(F[1],I2[0],acc[1][0]); acc[1][1]=MFMA(F[1],I2[1],acc[1][1]);
    if (csrc) {
      #pragma unroll
      for (int kb = 0; kb < 4; kb++) {
        const int ko = kb*32 + kof;
        short8 c0 = *(const short8*)(csrc + (mtg*32      + n16)*STR + ko);
        short8 c1 = *(const short8*)(csrc + (mtg*32 + 16 + n16)*STR + ko);
        acc[0][0]=MFMA(c0,Bs[0][kb],acc[0][0]); acc[0][1]=MFMA(c0,Bs[1][kb],acc[0][1]);
        acc[1][0]=MFMA(c1,Bs[0][kb],acc[1][0]); acc[1][1]=MFMA(c1,Bs[1][kb],acc[1][1]);
      }
    }
    #pragma unroll
    for (int i = 0; i < 2; i++) {
      const int p = mtg*8 + i*4 + quad;          // C row / 4 = parent idx
      #pragma unroll
      for (int j = 0; j < 2; j++) {
        const float bb = csrc ? bsv[j] : 0.f;
        f32x4 A = acc[i][j];
        float h0=A[0]+bb, h1=A[1]+bb, h2=A[2]+bb, h3=A[3]+bb;
        pm[j] = fmaxf(pm[j], fmaxf(fmaxf(h0,h1), fmaxf(h2,h3)));
        csdst[(csrow0 + p)*STR + ntg*32 + j*16 + n16] =
            f2bf(A[0]+A[1]+A[2]+A[3] + 4.f*bb);
      }
    }
  };

  __syncthreads();                   // TK visible
  issueF(FA, 0);
  /*leaf 0*/ issueF(FB, 64);  phase64(FA, nullptr, CS4,  0);
  /*leaf 1*/ issueF(FA, 128); phase64(FB, nullptr, CS4, 16);
  /*leaf 2*/ issueF(FB, 192); phase64(FA, nullptr, CS4, 32);
  /*leaf 3*/ issueF(FA, 256); phase64(FB, nullptr, CS4, 48); BAR();
  /*L4    */                  phase64(FA, CS4,     CS3q, 0); BAR();

  // CS3q -> G3 (coalesced, bit-identical bf16)
  if (tid < 256) {
    const int r = tid >> 4, p = tid & 15;
    *(short8*)(G3 + ((long)(b*64 + q*16 + r))*ED + p*8) =
        *(const short8*)(CS3q + r*STR + p*8);
  }

  // pm -> PM -> GPM (column c valid only in PM rows (c>>5) and (c>>5)+4)
  #pragma unroll
  for (int j = 0; j < 2; j++) {
    float v = pm[j];
    v = fmaxf(v, __shfl_xor(v, 16, 64));
    v = fmaxf(v, __shfl_xor(v, 32, 64));
    if (quad == 0) PM[w*128 + ntg*32 + j*16 + n16] = v;
  }
  __syncthreads();
  if (tid < 128) {
    const int c = tid, w0 = c >> 5;
    float m = fmaxf(PM[w0*128 + c], PM[(w0+4)*128 + c]);
    GPM[((long)b*4 + q)*ED + c] = m;
  }
}

// ---------------------------------------------------------------------------
// tree_tail: one block per tree. Stages G3 -> CS3 LDS, replays phases
// n=20..23 (L3 dual, L2, L1, root), merges GPM -> out.
// ---------------------------------------------------------------------------
__global__ __attribute__((amdgpu_flat_work_group_size(512, 512),
                          amdgpu_waves_per_eu(4, 4)))
void tree_tail(const int* __restrict__ tokens, const ushort* __restrict__ P,
               const float* __restrict__ WsW,  const float* __restrict__ Wsb,
               const ushort* __restrict__ G3, const float* __restrict__ GPM,
               float* __restrict__ out) {
  __shared__ int    TK[96];          // tokens 0..84
  __shared__ ushort CS3[64 * STR];
  __shared__ ushort CS2[16 * STR];   // row 0 reused as H1
  __shared__ ushort CS1[4 * STR];
  __shared__ float  PM[1024];

  const int tid = threadIdx.x;
  const int b   = blockIdx.x;
  const int w    = tid >> 6;
  const int lane = tid & 63;
  const int n16  = lane & 15;
  const int quad = lane >> 4;
  const int mtg  = w >> 2, ntg = w & 3;
  const int kof  = quad * 8;

  if (tid < 85) TK[tid] = tokens[(long)b*NTOK + tid];
  for (int i = tid; i < 1024; i += 512) {            // stage 64 G3 rows
    const int r = i >> 4, p = i & 15;
    *(short8*)(CS3 + r*STR + p*8) =
        *(const short8*)(G3 + ((long)(b*64 + r))*ED + p*8);
  }

  float bsv[2];
  #pragma unroll
  for (int j = 0; j < 2; j++) bsv[j] = 4.f * Wsb[ntg*32 + j*16 + n16];

  short8 Bs[2][4];
  #pragma unroll
  for (int jt = 0; jt < 2; jt++)
    #pragma unroll
    for (int kb = 0; kb < 4; kb++) {
      const float* pc = WsW + (ntg*32 + jt*16 + n16)*ED + kb*32 + kof;
      Bs[jt][kb] = pack8(((const float4*)pc)[0], ((const float4*)pc)[1]);
    }

  short8 I2[2];
  #pragma unroll
  for (int j = 0; j < 2; j++) {
    union { ushort us[8]; short8 s8; } t;
    #pragma unroll
    for (int e = 0; e < 8; e++) t.us[e] = 0;
    if (quad == 2*j + (n16 >> 3)) t.us[n16 & 7] = 0x3F80;
    I2[j] = t.s8;
  }

  float pm[2] = {0.f, 0.f};

  short8 FA[2], FB[2];
  auto issueF = [&](short8 (&F)[2], int ofs) {
    const int co = ntg*32 + kof;
    F[0] = *(const short8*)(P + (long)TK[ofs + mtg*32      + n16]*ED + co);
    F[1] = *(const short8*)(P + (long)TK[ofs + mtg*32 + 16 + n16]*ED + co);
  };
  auto issueS = [&](short8 (&F)[2], int ofs, int M) {
    if (mtg != 0) return;
    const int ar = (M == 16) ? n16 : ((M == 4) ? (n16 & 3) : 0);
    F[0] = *(const short8*)(P + (long)TK[ofs + ar]*ED + ntg*32 + kof);
  };

  auto phase64 = [&](const short8 (&F)[2], const ushort* csrc, ushort* csdst,
                     int csrow0) {
    f32x4 acc[2][2];
    #pragma unroll
    for (int i = 0; i < 2; i++)
      #pragma unroll
      for (int j = 0; j < 2; j++) acc[i][j] = (f32x4){0.f,0.f,0.f,0.f};
    acc[0][0]=MFMA(F[0],I2[0],acc[0][0]); acc[0][1]=MFMA(F[0],I2[1],acc[0][1]);
    acc[1][0]=MFMA(F[1],I2[0],acc[1][0]); acc[1][1]=MFMA(F[1],I2[1],acc[1][1]);
    #pragma unroll
    for (int kb = 0; kb < 4; kb++) {
      const int ko = kb*32 + kof;
      short8 c0 = *(const short8*)(csrc + (mtg*32      + n16)*STR + ko);
      short8 c1 = *(const short8*)(csrc + (mtg*32 + 16 + n16)*STR + ko);
      acc[0][0]=MFMA(c0,Bs[0][kb],acc[0][0]); acc[0][1]=MFMA(c0,Bs[1][kb],acc[0][1]);
      acc[1][0]=MFMA(c1,Bs[0][kb],acc[1][0]); acc[1][1]=MFMA(c1,Bs[1][kb],acc[1][1]);
    }
    #pragma unroll
    for (int i = 0; i < 2; i++) {
      const int p = mtg*8 + i*4 + quad;
      #pragma unroll
      for (int j = 0; j < 2; j++) {
        const float bb = bsv[j];
        f32x4 A = acc[i][j];
        float h0=A[0]+bb, h1=A[1]+bb, h2=A[2]+bb, h3=A[3]+bb;
        pm[j] = fmaxf(pm[j], fmaxf(fmaxf(h0,h1), fmaxf(h2,h3)));
        csdst[(csrow0 + p)*STR + ntg*32 + j*16 + n16] =
            f2bf(A[0]+A[1]+A[2]+A[3] + 4.f*bb);
      }
    }
  };

  auto smallphase = [&](short8 a, const ushort* csrc, int M, ushort* csdst) {
    if (mtg != 0) return;
    const int ar = (M == 16) ? n16 : ((M == 4) ? (n16 & 3) : 0);
    f32x4 acc[2];
    acc[0] = (f32x4){0.f,0.f,0.f,0.f}; acc[1] = (f32x4){0.f,0.f,0.f,0.f};
    acc[0] = MFMA(a, I2[0], acc[0]); acc[1] = MFMA(a, I2[1], acc[1]);
    #pragma unroll
    for (int kb = 0; kb < 4; kb++) {
      const int ko = kb*32 + kof;
      short8 c2 = *(const short8*)(csrc + ar*STR + ko);
      acc[0] = MFMA(c2, Bs[0][kb], acc[0]); acc[1] = MFMA(c2, Bs[1][kb], acc[1]);
    }
    #pragma unroll
    for (int j = 0; j < 2; j++) {
      const float bb = bsv[j];
      f32x4 A = acc[j];
      const int c = ntg*32 + j*16 + n16;
      if (M == 16) {
        float h0=A[0]+bb, h1=A[1]+bb, h2=A[2]+bb, h3=A[3]+bb;
        pm[j] = fmaxf(pm[j], fmaxf(fmaxf(h0,h1), fmaxf(h2,h3)));
        csdst[quad*STR + c] = f2bf(A[0]+A[1]+A[2]+A[3] + 4.f*bb);
      } else if (M == 4) {
        if (quad == 0) {
          float h0=A[0]+bb, h1=A[1]+bb, h2=A[2]+bb, h3=A[3]+bb;
          pm[j] = fmaxf(pm[j], fmaxf(fmaxf(h0,h1), fmaxf(h2,h3)));
          csdst[c] = f2bf(A[0]+A[1]+A[2]+A[3] + 4.f*bb);   // H1
        }
      } else {
        if (quad == 0) pm[j] = fmaxf(pm[j], A[0] + bb);    // root h0
      }
    }
  };

  __syncthreads();                    // TK + CS3 visible
  issueF(FA, 21);
  /*L3 dual*/ issueS(FB, 5, 16);  phase64(FA, CS3, CS2, 0);        BAR();
  /*L2 M=16*/ issueS(FA, 1, 4);   smallphase(FB[0], CS2, 16, CS1); BAR();
  /*L1 M=4 */ issueS(FB, 0, 1);   smallphase(FA[0], CS1, 4,  CS2); BAR();
  /*root   */                     smallphase(FB[0], CS2, 1,  nullptr);

  #pragma unroll
  for (int j = 0; j < 2; j++) {
    float v = pm[j];
    v = fmaxf(v, __shfl_xor(v, 16, 64));
    v = fmaxf(v, __shfl_xor(v, 32, 64));
    if (quad == 0) PM[w*128 + ntg*32 + j*16 + n16] = v;
  }
  __syncthreads();
  if (tid < 128) {
    const int c = tid, w0 = c >> 5;
    float m = fmaxf(PM[w0*128 + c], PM[(w0+4)*128 + c]);
    #pragma unroll
    for (int q = 0; q < 4; q++) m = fmaxf(m, GPM[((long)b*4 + q)*ED + c]);
    out[(long)b*ED + c] = m;
  }
}

// ---------------------------------------------------------------------------
// Fallback: round-0 verified kernel, unchanged (used if ws_size too small).
// ---------------------------------------------------------------------------
#define SM_BYTES (4096 + 404 * STR * 2)

__global__ __attribute__((amdgpu_flat_work_group_size(512, 512),
                          amdgpu_waves_per_eu(2, 8)))
void tree_kernel(
    const int* __restrict__ tokens, const float* __restrict__ emb,
    const float* __restrict__ WcW,  const float* __restrict__ Wcb,
    const float* __restrict__ WsW,  const float* __restrict__ Wsb,
    float* __restrict__ out) {
  extern __shared__ char smem[];
  float*  PM  = (float*)smem;
  ushort* WsL = (ushort*)(PM + 1024);
  ushort* Xe0 = WsL + 128*STR;
  ushort* Xe1 = Xe0 + 64*STR;
  ushort* CS4 = Xe1 + 64*STR;
  ushort* CS3 = CS4 + 64*STR;
  ushort* CS2 = CS3 + 64*STR;
  ushort* CS1 = CS2 + 16*STR;

  const int  tid = threadIdx.x;
  const int  b   = blockIdx.x;
  const long tokbase = (long)b * NTOK;
  const int  w    = tid >> 6;
  const int  lane = tid & 63;
  const int  n16  = lane & 15;
  const int  quad = lane >> 4;
  const int  mtg  = w >> 2, ntg = w & 3;
  const int  kof  = quad * 8;

  float bcv[2], bsv[2];
  #pragma unroll
  for (int j = 0; j < 2; j++) {
    const int c = ntg*32 + j*16 + n16;
    bcv[j] = Wcb[c]; bsv[j] = 4.f * Wsb[c];
  }

  short8 Bc[2][4];
  #pragma unroll
  for (int jt = 0; jt < 2; jt++)
    #pragma unroll
    for (int kb = 0; kb < 4; kb++) {
      const float* pc = WcW + (ntg*32 + jt*16 + n16)*ED + kb*32 + kof;
      Bc[jt][kb] = pack8(((const float4*)pc)[0], ((const float4*)pc)[1]);
    }

  #pragma unroll
  for (int i = 0; i < 8; i++) {
    const int idx = tid + i*512;
    float4 f = ((const float4*)WsW)[idx];
    *(ushort4*)(WsL + (idx >> 5)*STR + ((idx & 31) << 2)) = cvt4(f);
  }

  for (int i = tid; i < 1024; i += 512) PM[i] = 0.f;
  float pm[2] = {0.f, 0.f};

  float4 RA[4], RB[4];
  auto issue64 = [&](float4 (&R)[4], int ofs) {
    const int r = tid >> 3, p = tid & 7;
    const float4* src = (const float4*)(emb + (long)tokens[tokbase + ofs + r]*ED) + (p << 2);
    R[0] = src[0]; R[1] = src[1]; R[2] = src[2]; R[3] = src[3];
  };
  auto store64 = [&](const float4 (&R)[4], ushort* Xe) {
    const int r = tid >> 3, p = tid & 7;
    short8* d = (short8*)(Xe + r*STR + (p << 4));
    d[0] = pack8(R[0], R[1]); d[1] = pack8(R[2], R[3]);
  };
  auto issueN = [&](float4 (&R)[4], int ofs, int nrows) {
    const int r = tid >> 5, p = tid & 31;
    if (r < nrows) R[0] = ((const float4*)(emb + (long)tokens[tokbase + ofs + r]*ED))[p];
  };
  auto storeN = [&](const float4 (&R)[4], ushort* Xe, int nrows) {
    const int r = tid >> 5, p = tid & 31;
    if (r < nrows) *(ushort4*)(Xe + r*STR + (p << 2)) = cvt4(R[0]);
  };

  auto phase64 = [&](const ushort* Xe, const ushort* csrc, ushort* csdst, int csrow0) {
    f32x4 acc[2][2];
    #pragma unroll
    for (int i = 0; i < 2; i++)
      #pragma unroll
      for (int j = 0; j < 2; j++) acc[i][j] = (f32x4){0.f,0.f,0.f,0.f};
    #pragma unroll
    for (int kb = 0; kb < 4; kb++) {
      const int ko = kb*32 + kof;
      short8 a0 = *(const short8*)(Xe + (mtg*32      + n16)*STR + ko);
      short8 a1 = *(const short8*)(Xe + (mtg*32 + 16 + n16)*STR + ko);
      acc[0][0]=MFMA(a0,Bc[0][kb],acc[0][0]); acc[0][1]=MFMA(a0,Bc[1][kb],acc[0][1]);
      acc[1][0]=MFMA(a1,Bc[0][kb],acc[1][0]); acc[1][1]=MFMA(a1,Bc[1][kb],acc[1][1]);
      if (csrc) {
        short8 c0 = *(const short8*)(csrc + (mtg*32      + n16)*STR + ko);
        short8 c1 = *(const short8*)(csrc + (mtg*32 + 16 + n16)*STR + ko);
        short8 s0 = *(const short8*)(WsL  + (ntg*32      + n16)*STR + ko);
        short8 s1 = *(const short8*)(WsL  + (ntg*32 + 16 + n16)*STR + ko);
        acc[0][0]=MFMA(c0,s0,acc[0][0]); acc[0][1]=MFMA(c0,s1,acc[0][1]);
        acc[1][0]=MFMA(c1,s0,acc[1][0]); acc[1][1]=MFMA(c1,s1,acc[1][1]);
      }
    }
    #pragma unroll
    for (int i = 0; i < 2; i++) {
      const int p = mtg*8 + i*4 + quad;
      #pragma unroll
      for (int j = 0; j < 2; j++) {
        const float bb = csrc ? (bcv[j] + bsv[j]) : bcv[j];
        f32x4 A = acc[i][j];
        float h0=A[0]+bb, h1=A[1]+bb, h2=A[2]+bb, h3=A[3]+bb;
        pm[j] = fmaxf(pm[j], fmaxf(fmaxf(h0,h1), fmaxf(h2,h3)));
        csdst[(csrow0 + p)*STR + ntg*32 + j*16 + n16] =
            f2bf(A[0]+A[1]+A[2]+A[3] + 4.f*bb);
      }
    }
  };

  auto smallphase = [&](const ushort* Xe, const ushort* csrc, int M, ushort* csdst) {
    if (mtg != 0) return;
    const int ar = (M == 16) ? n16 : ((M == 4) ? (n16 & 3) : 0);
    f32x4 acc[2];
    acc[0] = (f32x4){0.f,0.f,0.f,0.f}; acc[1] = (f32x4){0.f,0.f,0.f,0.f};
    #pragma unroll
    for (int kb = 0; kb < 4; kb++) {
      const int ko = kb*32 + kof;
      short8 a  = *(const short8*)(Xe   + ar*STR + ko);
      short8 c2 = *(const short8*)(csrc + ar*STR + ko);
      short8 s0 = *(const short8*)(WsL + (ntg*32      + n16)*STR + ko);
      short8 s1 = *(const short8*)(WsL + (ntg*32 + 16 + n16)*STR + ko);
      acc[0] = MFMA(a,  Bc[0][kb], acc[0]); acc[1] = MFMA(a,  Bc[1][kb], acc[1]);
      acc[0] = MFMA(c2, s0, acc[0]);        acc[1] = MFMA(c2, s1, acc[1]);
    }
    #pragma unroll
    for (int j = 0; j < 2; j++) {
      const float bb = bcv[j] + bsv[j];
      f32x4 A = acc[j];
      const int c = ntg*32 + j*16 + n16;
      if (M == 16) {
        float h0=A[0]+bb, h1=A[1]+bb, h2=A[2]+bb, h3=A[3]+bb;
        pm[j] = fmaxf(pm[j], fmaxf(fmaxf(h0,h1), fmaxf(h2,h3)));
        csdst[quad*STR + c] = f2bf(A[0]+A[1]+A[2]+A[3] + 4.f*bb);
      } else if (M == 4) {
        if (quad == 0) {
          float h0=A[0]+bb, h1=A[1]+bb, h2=A[2]+bb, h3=A[3]+bb;
          pm[j] = fmaxf(pm[j], fmaxf(fmaxf(h0,h1), fmaxf(h2,h3)));
          csdst[c] = f2bf(A[0]+A[1]+A[2]+A[3] + 4.f*bb);
        }
      } else {
        if (quad == 0) pm[j] = fmaxf(pm[j], A[0] + bb);
      }
    }
  };

  issue64(RA, 341);
  issue64(RB, 341 + 64);
  store64(RA, Xe0);
  __syncthreads();
  issue64(RA, 341+128);     phase64(Xe0, nullptr, CS4,  0); store64(RB, Xe1); __syncthreads();
  issue64(RB, 341+192);     phase64(Xe1, nullptr, CS4, 16); store64(RA, Xe0); __syncthreads();
  issue64(RA, 85);          phase64(Xe0, nullptr, CS4, 32); store64(RB, Xe1); __syncthreads();
  issue64(RB, 341+256);     phase64(Xe1, nullptr, CS4, 48); store64(RA, Xe0); __syncthreads();
  issue64(RA, 341+256+64);  phase64(Xe0, CS4,     CS3,  0); store64(RB, Xe1); __syncthreads();
  issue64(RB, 341+256+128); phase64(Xe1, nullptr, CS4,  0); store64(RA, Xe0); __syncthreads();
  issue64(RA, 341+256+192); phase64(Xe0, nullptr, CS4, 16); store64(RB, Xe1); __syncthreads();
  issue64(RB, 85+64);       phase64(Xe1, nullptr, CS4, 32); store64(RA, Xe0); __syncthreads();
  issue64(RA, 341+512);     phase64(Xe0, nullptr, CS4, 48); store64(RB, Xe1); __syncthreads();
  issue64(RB, 341+512+64);  phase64(Xe1, CS4,     CS3, 16); store64(RA, Xe0); __syncthreads();
  issue64(RA, 341+512+128); phase64(Xe0, nullptr, CS4,  0); store64(RB, Xe1); __syncthreads();
  issue64(RB, 341+512+192); phase64(Xe1, nullptr, CS4, 16); store64(RA, Xe0); __syncthreads();
  issue64(RA, 85+128);      phase64(Xe0, nullptr, CS4, 32); store64(RB, Xe1); __syncthreads();
  issue64(RB, 341+768);     phase64(Xe1, nullptr, CS4, 48); store64(RA, Xe0); __syncthreads();
  issue64(RA, 341+768+64);  phase64(Xe0, CS4,     CS3, 32); store64(RB, Xe1); __syncthreads();
  issue64(RB, 341+768+128); phase64(Xe1, nullptr, CS4,  0); store64(RA, Xe0); __syncthreads();
  issue64(RA, 341+768+192); phase64(Xe0, nullptr, CS4, 16); store64(RB, Xe1); __syncthreads();
  issue64(RB, 85+192);      phase64(Xe1, nullptr, CS4, 32); store64(RA, Xe0); __syncthreads();
  issue64(RA, 21);          phase64(Xe0, nullptr, CS4, 48); store64(RB, Xe1); __syncthreads();
  issueN(RB, 5, 16);        phase64(Xe1, CS4,     CS3, 48); store64(RA, Xe0); __syncthreads();
  issueN(RA, 1, 4);         phase64(Xe0, CS3,     CS2,  0); storeN(RB, Xe1, 16); __syncthreads();
  issueN(RB, 0, 1);         smallphase(Xe1, CS2, 16, CS1);  storeN(RA, Xe0, 4);  __syncthreads();
                            smallphase(Xe0, CS1, 4,  CS2);  storeN(RB, Xe1, 1);  __syncthreads();
                            smallphase(Xe1, CS2, 1,  nullptr);

  #pragma unroll
  for (int j = 0; j < 2; j++) {
    float v = pm[j];
    v = fmaxf(v, __shfl_xor(v, 16, 64));
    v = fmaxf(v, __shfl_xor(v, 32, 64));
    if (quad == 0) PM[w*128 + ntg*32 + j*16 + n16] = v;
  }
  __syncthreads();
  if (tid < 128) {
    float m = 0.f;
    #pragma unroll
    for (int r = 0; r < 8; r++) m = fmaxf(m, PM[r*128 + tid]);
    out[(long)b*ED + tid] = m;
  }
}

extern "C" void kernel_launch(void* const* d_in, const int* in_sizes, int n_in,
                              void* d_out, int out_size, void* d_ws, size_t ws_size,
                              hipStream_t stream) {
  const int*   tokens = (const int*)d_in[0];
  const float* emb    = (const float*)d_in[1];
  const float* WcW    = (const float*)d_in[2];
  const float* Wcb    = (const float*)d_in[3];
  const float* WsW    = (const float*)d_in[4];
  const float* Wsb    = (const float*)d_in[5];
  float* out = (float*)d_out;

  if (d_ws != nullptr && ws_size >= WS_NEED) {
    ushort* P   = (ushort*)d_ws;
    ushort* G3  = (ushort*)((char*)d_ws + G3_OFF);
    float*  GPM = (float*)((char*)d_ws + GPM_OFF);
    proj_kernel<<<(VROWS + 63) / 64, 256, 0, stream>>>(emb, WcW, Wcb, P);
    tree_q<<<2048, 512, 0, stream>>>(tokens, P, WsW, Wsb, G3, GPM);
    tree_tail<<<512, 512, 0, stream>>>(tokens, P, WsW, Wsb, G3, GPM, out);
  } else {
    hipFuncSetAttribute(reinterpret_cast<const void*>(tree_kernel),
                        hipFuncAttributeMaxDynamicSharedMemorySize, SM_BYTES);
    tree_kernel<<<512, 512, SM_BYTES, stream>>>(tokens, emb, WcW, Wcb, WsW, Wsb, out);
  }
}

// Round 7
// 124.258 us; speedup vs baseline: 1.4727x; 1.4727x over previous
//
#include <hip/hip_runtime.h>
#include <hip/hip_bf16.h>

// B=512, A=4, D=6, N=1365, E=128. Level starts {0,1,5,21,85,341}.
// Round 7: REVERT to the round-4 verified best (125.3 us). R6's quarter-split
// (tree_q grid 2048 + tree_tail) regressed to 183 us: prologue replication
// (268 MB WsW L2 re-reads, VALUBusy 2.4->22.8%) and the random 64-B-segment
// gather is fabric-saturated (~4.5 TB/s delivered ceiling) -> more waves
// LOWERED delivered BW (2.4 TB/s). Composite roofline: ~70 us harness fills
// + ~38 us gather floor (179 MB random @ 4.5 TB/s) + ~10 us proj ~= 120-125.
// This file == R4: P=emb@Wc^T+b precomputed bf16 (proj, LDS-staged A-tile);
// tree_kernel_p with identity-MFMA injection, Ws in VGPRs, token preload,
// lgkm-only fence barriers (pure builtins; inline asm would trigger
// mayUseAGPRs -> VGPR budget halved -> spills, the R2/R3 failure).
// Fallback: if ws_size < 12.8 MB, run the round-0 verified kernel unchanged.
#define NTOK 1365
#define ED   128
#define STR  136   // bf16 LDS row stride: 272 B, 16B-aligned, balanced banks
#define VROWS 50000
#define PROWS 50048

typedef __attribute__((ext_vector_type(8))) short short8;
typedef __attribute__((ext_vector_type(4))) float f32x4;

#define MFMA(a,b,c) __builtin_amdgcn_mfma_f32_16x16x32_bf16((a),(b),(c),0,0,0)

// LDS-scoped release/acquire around a raw barrier: emits s_waitcnt lgkmcnt(0)
// (not vmcnt) before s_barrier, keeping global gathers in flight. Pure
// intrinsics -> no inline asm -> no conservative AGPR-split (R2/R3 cause).
#define BAR() do {                                                   \
    __builtin_amdgcn_fence(__ATOMIC_RELEASE, "workgroup", "local");  \
    __builtin_amdgcn_s_barrier();                                    \
    __builtin_amdgcn_fence(__ATOMIC_ACQUIRE, "workgroup", "local");  \
  } while (0)

__device__ __forceinline__ ushort f2bf(float f) {  // round-to-nearest-even
  union { float f; unsigned u; } v; v.f = f;
  unsigned r = v.u + 0x7fffu + ((v.u >> 16) & 1u);
  return (ushort)(r >> 16);
}
__device__ __forceinline__ ushort4 cvt4(float4 f) {
  ushort4 u; u.x = f2bf(f.x); u.y = f2bf(f.y); u.z = f2bf(f.z); u.w = f2bf(f.w);
  return u;
}
__device__ __forceinline__ short8 pack8(float4 a, float4 b) {
  union { ushort us[8]; short8 s8; } t;
  t.us[0]=f2bf(a.x); t.us[1]=f2bf(a.y); t.us[2]=f2bf(a.z); t.us[3]=f2bf(a.w);
  t.us[4]=f2bf(b.x); t.us[5]=f2bf(b.y); t.us[6]=f2bf(b.z); t.us[7]=f2bf(b.w);
  return t.s8;
}

// ---------------------------------------------------------------------------
// proj_kernel: P[v][c] = (emb @ Wc^T)[v][c] + Wcb[c], bf16. 782 blocks x 256.
// A-tile (64 emb rows) staged in LDS once per block.
// ---------------------------------------------------------------------------
__global__ __attribute__((amdgpu_flat_work_group_size(256, 256)))
void proj_kernel(const float* __restrict__ emb, const float* __restrict__ WcW,
                 const float* __restrict__ Wcb, ushort* __restrict__ P) {
  __shared__ ushort At[64 * STR];
  const int tid = threadIdx.x, w = tid >> 6, lane = tid & 63;
  const int n16 = lane & 15, quad = lane >> 4, kof = quad * 8;
  const int m0 = blockIdx.x * 64;

  // stage 64 rows (bf16) cooperatively: 2048 float4 / 256 thr = 8 each
  #pragma unroll
  for (int i = 0; i < 8; i++) {
    const int idx = tid + i*256;
    const int r = idx >> 5, c4 = idx & 31;
    int arow = m0 + r; if (arow >= VROWS) arow = 0;      // pad rows safe
    float4 f = ((const float4*)(emb + (long)arow*ED))[c4];
    *(ushort4*)(At + r*STR + (c4 << 2)) = cvt4(f);
  }

  float bv[2];
  short8 Bp[2][4];
  #pragma unroll
  for (int j = 0; j < 2; j++) {
    const int c = w*32 + j*16 + n16;
    bv[j] = Wcb[c];
    #pragma unroll
    for (int kb = 0; kb < 4; kb++) {
      const float* pc = WcW + c*ED + kb*32 + kof;
      Bp[j][kb] = pack8(((const float4*)pc)[0], ((const float4*)pc)[1]);
    }
  }
  __syncthreads();

  #pragma unroll
  for (int i = 0; i < 4; i++) {
    f32x4 acc0 = (f32x4){0.f,0.f,0.f,0.f}, acc1 = (f32x4){0.f,0.f,0.f,0.f};
    #pragma unroll
    for (int kb = 0; kb < 4; kb++) {
      short8 a = *(const short8*)(At + (i*16 + n16)*STR + kb*32 + kof);
      acc0 = MFMA(a, Bp[0][kb], acc0);
      acc1 = MFMA(a, Bp[1][kb], acc1);
    }
    #pragma unroll
    for (int r = 0; r < 4; r++) {
      const int orow = m0 + i*16 + quad*4 + r;   // C layout: row=quad*4+reg
      if (orow < VROWS) {
        P[(long)orow*ED + w*32 + n16]      = f2bf(acc0[r] + bv[0]);
        P[(long)orow*ED + w*32 + 16 + n16] = f2bf(acc1[r] + bv[1]);
      }
    }
  }
}

// ---------------------------------------------------------------------------
// tree_kernel_p: bf16 P gathers; identity-MFMA injection; Ws in VGPRs.
// LDS: TK 5472 B + 276 rows * 272 B = 80544 B -> 2 blocks/CU.
// PM (4 KB) overlays CS4 (dead after phase 19; init in phase-20 slot).
// waves_per_eu(4,4): VGPR budget 128 (demand ~105). NO inline asm anywhere.
// ---------------------------------------------------------------------------
#define TKB 5472                         // 1365 ints padded to 16B multiple
#define SMP_BYTES (TKB + 276 * STR * 2)

__global__ __attribute__((amdgpu_flat_work_group_size(512, 512),
                          amdgpu_waves_per_eu(4, 4)))
void tree_kernel_p(
    const int* __restrict__ tokens, const ushort* __restrict__ P,
    const float* __restrict__ WsW,  const float* __restrict__ Wsb,
    float* __restrict__ out) {
  extern __shared__ char smem[];
  int*    TK  = (int*)smem;              // block's 1365 tokens
  ushort* Xe0 = (ushort*)(smem + TKB);   // staging buf 0 (64 rows)
  ushort* Xe1 = Xe0 + 64*STR;            // staging buf 1
  ushort* CS4 = Xe1 + 64*STR;            // leaf child-sums (per quarter)
  ushort* CS3 = CS4 + 64*STR;            // 64 rows (= L3 node idx)
  ushort* CS2 = CS3 + 64*STR;            // 16 rows; row 0 reused as H1
  ushort* CS1 = CS2 + 16*STR;            // 4 rows
  float*  PM  = (float*)CS4;             // overlaid: used only after phase 19

  const int  tid = threadIdx.x;
  const int  b   = blockIdx.x;
  const int  w    = tid >> 6;
  const int  lane = tid & 63;
  const int  n16  = lane & 15;
  const int  quad = lane >> 4;
  const int  mtg  = w >> 2, ntg = w & 3;
  const int  kof  = quad * 8;

  // preload tokens to LDS (removes per-phase vmcnt on address resolution)
  {
    const long tokbase = (long)b * NTOK;
    for (int i = tid; i < NTOK; i += 512) TK[i] = tokens[tokbase + i];
  }

  // P already contains Wc_b; only Ws bias remains.
  float bsv[2];
  #pragma unroll
  for (int j = 0; j < 2; j++) bsv[j] = 4.f * Wsb[ntg*32 + j*16 + n16];

  // ---- Ws fragments resident in VGPRs ----
  short8 Bs[2][4];
  #pragma unroll
  for (int jt = 0; jt < 2; jt++)
    #pragma unroll
    for (int kb = 0; kb < 4; kb++) {
      const float* pc = WsW + (ntg*32 + jt*16 + n16)*ED + kb*32 + kof;
      Bs[jt][kb] = pack8(((const float4*)pc)[0], ((const float4*)pc)[1]);
    }

  // ---- identity B-fragments: B_j[n][k] = 1 iff k == j*16+n (bf16 1.0) ----
  short8 I2[2];
  #pragma unroll
  for (int j = 0; j < 2; j++) {
    union { ushort us[8]; short8 s8; } t;
    #pragma unroll
    for (int e = 0; e < 8; e++) t.us[e] = 0;
    if (quad == 2*j + (n16 >> 3)) t.us[n16 & 7] = 0x3F80;
    I2[j] = t.s8;
  }

  float pm[2] = {0.f, 0.f};

  // ---- depth-2 pipelined bf16 gathers (256 B/row, 8 thr/row) ----
  short8 RA[2], RB[2];
  auto issue64 = [&](short8 (&R)[2], int ofs) {
    const int r = tid >> 3, p = tid & 7;
    const short8* src = (const short8*)(P + (long)TK[ofs + r]*ED) + (p << 1);
    R[0] = src[0]; R[1] = src[1];
  };
  auto store64 = [&](const short8 (&R)[2], ushort* Xe) {
    const int r = tid >> 3, p = tid & 7;
    short8* d = (short8*)(Xe + r*STR + (p << 4));
    d[0] = R[0]; d[1] = R[1];
  };
  auto issueN = [&](short8 (&R)[2], int ofs, int nrows) { // 32 thr/row, 8 B
    const int r = tid >> 5, p = tid & 31;
    if (r < nrows) {
      ushort4 v = *((const ushort4*)(P + (long)TK[ofs + r]*ED) + p);
      R[0][0] = (short)v.x; R[0][1] = (short)v.y;
      R[0][2] = (short)v.z; R[0][3] = (short)v.w;
    }
  };
  auto storeN = [&](const short8 (&R)[2], ushort* Xe, int nrows) {
    const int r = tid >> 5, p = tid & 31;
    if (r < nrows) {
      ushort4 v; v.x = (ushort)R[0][0]; v.y = (ushort)R[0][1];
      v.z = (ushort)R[0][2]; v.w = (ushort)R[0][3];
      *(ushort4*)(Xe + r*STR + (p << 2)) = v;
    }
  };

  // ---- M=64 phase: acc = Xe (identity MFMA) + csrc@Ws^T; relu-max + sums ----
  auto phase64 = [&](const ushort* Xe, const ushort* csrc, ushort* csdst, int csrow0) {
    f32x4 acc[2][2];
    #pragma unroll
    for (int i = 0; i < 2; i++)
      #pragma unroll
      for (int j = 0; j < 2; j++) acc[i][j] = (f32x4){0.f,0.f,0.f,0.f};
    {
      const int ko = ntg*32 + kof;   // only the k-window owning our columns
      short8 a0 = *(const short8*)(Xe + (mtg*32      + n16)*STR + ko);
      short8 a1 = *(const short8*)(Xe + (mtg*32 + 16 + n16)*STR + ko);
      acc[0][0]=MFMA(a0,I2[0],acc[0][0]); acc[0][1]=MFMA(a0,I2[1],acc[0][1]);
      acc[1][0]=MFMA(a1,I2[0],acc[1][0]); acc[1][1]=MFMA(a1,I2[1],acc[1][1]);
    }
    if (csrc) {
      #pragma unroll
      for (int kb = 0; kb < 4; kb++) {
        const int ko = kb*32 + kof;
        short8 c0 = *(const short8*)(csrc + (mtg*32      + n16)*STR + ko);
        short8 c1 = *(const short8*)(csrc + (mtg*32 + 16 + n16)*STR + ko);
        acc[0][0]=MFMA(c0,Bs[0][kb],acc[0][0]); acc[0][1]=MFMA(c0,Bs[1][kb],acc[0][1]);
        acc[1][0]=MFMA(c1,Bs[0][kb],acc[1][0]); acc[1][1]=MFMA(c1,Bs[1][kb],acc[1][1]);
      }
    }
    #pragma unroll
    for (int i = 0; i < 2; i++) {
      const int p = mtg*8 + i*4 + quad;          // C row / 4 = parent idx
      #pragma unroll
      for (int j = 0; j < 2; j++) {
        const float bb = csrc ? bsv[j] : 0.f;
        f32x4 A = acc[i][j];
        float h0=A[0]+bb, h1=A[1]+bb, h2=A[2]+bb, h3=A[3]+bb;
        pm[j] = fmaxf(pm[j], fmaxf(fmaxf(h0,h1), fmaxf(h2,h3)));
        csdst[(csrow0 + p)*STR + ntg*32 + j*16 + n16] =
            f2bf(A[0]+A[1]+A[2]+A[3] + 4.f*bb);
      }
    }
  };

  // ---- small phases (mtg==0 waves only) ----
  auto smallphase = [&](const ushort* Xe, const ushort* csrc, int M, ushort* csdst) {
    if (mtg != 0) return;
    const int ar = (M == 16) ? n16 : ((M == 4) ? (n16 & 3) : 0);
    f32x4 acc[2];
    acc[0] = (f32x4){0.f,0.f,0.f,0.f}; acc[1] = (f32x4){0.f,0.f,0.f,0.f};
    {
      const int ko = ntg*32 + kof;
      short8 a = *(const short8*)(Xe + ar*STR + ko);
      acc[0] = MFMA(a, I2[0], acc[0]); acc[1] = MFMA(a, I2[1], acc[1]);
    }
    #pragma unroll
    for (int kb = 0; kb < 4; kb++) {
      const int ko = kb*32 + kof;
      short8 c2 = *(const short8*)(csrc + ar*STR + ko);
      acc[0] = MFMA(c2, Bs[0][kb], acc[0]); acc[1] = MFMA(c2, Bs[1][kb], acc[1]);
    }
    #pragma unroll
    for (int j = 0; j < 2; j++) {
      const float bb = bsv[j];
      f32x4 A = acc[j];
      const int c = ntg*32 + j*16 + n16;
      if (M == 16) {
        float h0=A[0]+bb, h1=A[1]+bb, h2=A[2]+bb, h3=A[3]+bb;
        pm[j] = fmaxf(pm[j], fmaxf(fmaxf(h0,h1), fmaxf(h2,h3)));
        csdst[quad*STR + c] = f2bf(A[0]+A[1]+A[2]+A[3] + 4.f*bb);
      } else if (M == 4) {
        if (quad == 0) {
          float h0=A[0]+bb, h1=A[1]+bb, h2=A[2]+bb, h3=A[3]+bb;
          pm[j] = fmaxf(pm[j], fmaxf(fmaxf(h0,h1), fmaxf(h2,h3)));
          csdst[c] = f2bf(A[0]+A[1]+A[2]+A[3] + 4.f*bb);   // H1
        }
      } else {
        if (quad == 0) pm[j] = fmaxf(pm[j], A[0] + bb);    // root h0
      }
    }
  };

  // ---- explicit 24-phase driver ----
  __syncthreads();                   // TK visible (full sync OK in prologue)
  issue64(RA, 341);
  issue64(RB, 341 + 64);
  store64(RA, Xe0);
  BAR();
  /*n=0 */ issue64(RA, 341+128);     phase64(Xe0, nullptr, CS4,  0); store64(RB, Xe1); BAR();
  /*n=1 */ issue64(RB, 341+192);     phase64(Xe1, nullptr, CS4, 16); store64(RA, Xe0); BAR();
  /*n=2 */ issue64(RA, 85);          phase64(Xe0, nullptr, CS4, 32); store64(RB, Xe1); BAR();
  /*n=3 */ issue64(RB, 341+256);     phase64(Xe1, nullptr, CS4, 48); store64(RA, Xe0); BAR();
  /*n=4 */ issue64(RA, 341+256+64);  phase64(Xe0, CS4,     CS3,  0); store64(RB, Xe1); BAR();
  /*n=5 */ issue64(RB, 341+256+128); phase64(Xe1, nullptr, CS4,  0); store64(RA, Xe0); BAR();
  /*n=6 */ issue64(RA, 341+256+192); phase64(Xe0, nullptr, CS4, 16); store64(RB, Xe1); BAR();
  /*n=7 */ issue64(RB, 85+64);       phase64(Xe1, nullptr, CS4, 32); store64(RA, Xe0); BAR();
  /*n=8 */ issue64(RA, 341+512);     phase64(Xe0, nullptr, CS4, 48); store64(RB, Xe1); BAR();
  /*n=9 */ issue64(RB, 341+512+64);  phase64(Xe1, CS4,     CS3, 16); store64(RA, Xe0); BAR();
  /*n=10*/ issue64(RA, 341+512+128); phase64(Xe0, nullptr, CS4,  0); store64(RB, Xe1); BAR();
  /*n=11*/ issue64(RB, 341+512+192); phase64(Xe1, nullptr, CS4, 16); store64(RA, Xe0); BAR();
  /*n=12*/ issue64(RA, 85+128);      phase64(Xe0, nullptr, CS4, 32); store64(RB, Xe1); BAR();
  /*n=13*/ issue64(RB, 341+768);     phase64(Xe1, nullptr, CS4, 48); store64(RA, Xe0); BAR();
  /*n=14*/ issue64(RA, 341+768+64);  phase64(Xe0, CS4,     CS3, 32); store64(RB, Xe1); BAR();
  /*n=15*/ issue64(RB, 341+768+128); phase64(Xe1, nullptr, CS4,  0); store64(RA, Xe0); BAR();
  /*n=16*/ issue64(RA, 341+768+192); phase64(Xe0, nullptr, CS4, 16); store64(RB, Xe1); BAR();
  /*n=17*/ issue64(RB, 85+192);      phase64(Xe1, nullptr, CS4, 32); store64(RA, Xe0); BAR();
  /*n=18*/ issue64(RA, 21);          phase64(Xe0, nullptr, CS4, 48); store64(RB, Xe1); BAR();
  /*n=19*/ issueN(RB, 5, 16);        phase64(Xe1, CS4,     CS3, 48); store64(RA, Xe0); BAR();
  /*n=20: CS4 now dead -> init PM (overlay) behind this phase's barrier */
  issueN(RA, 1, 4);                  phase64(Xe0, CS3,     CS2,  0);
  for (int i = tid; i < 1024; i += 512) PM[i] = 0.f;
  storeN(RB, Xe1, 16); BAR();
  /*n=21*/ issueN(RB, 0, 1);         smallphase(Xe1, CS2, 16, CS1);  storeN(RA, Xe0, 4);  BAR();
  /*n=22*/                           smallphase(Xe0, CS1, 4,  CS2);  storeN(RB, Xe1, 1);  BAR();
  /*n=23*/                           smallphase(Xe1, CS2, 1,  nullptr);

  // ---- merge per-lane maxima -> PM -> out ----
  #pragma unroll
  for (int j = 0; j < 2; j++) {
    float v = pm[j];
    v = fmaxf(v, __shfl_xor(v, 16, 64));
    v = fmaxf(v, __shfl_xor(v, 32, 64));
    if (quad == 0) PM[w*128 + ntg*32 + j*16 + n16] = v;
  }
  __syncthreads();
  if (tid < 128) {
    float m = 0.f;
    #pragma unroll
    for (int r = 0; r < 8; r++) m = fmaxf(m, PM[r*128 + tid]);
    out[(long)b*ED + tid] = m;
  }
}

// ---------------------------------------------------------------------------
// Fallback: round-0 verified kernel, unchanged (used if ws_size too small).
// ---------------------------------------------------------------------------
#define SM_BYTES (4096 + 404 * STR * 2)

__global__ __attribute__((amdgpu_flat_work_group_size(512, 512),
                          amdgpu_waves_per_eu(2, 8)))
void tree_kernel(
    const int* __restrict__ tokens, const float* __restrict__ emb,
    const float* __restrict__ WcW,  const float* __restrict__ Wcb,
    const float* __restrict__ WsW,  const float* __restrict__ Wsb,
    float* __restrict__ out) {
  extern __shared__ char smem[];
  float*  PM  = (float*)smem;
  ushort* WsL = (ushort*)(PM + 1024);
  ushort* Xe0 = WsL + 128*STR;
  ushort* Xe1 = Xe0 + 64*STR;
  ushort* CS4 = Xe1 + 64*STR;
  ushort* CS3 = CS4 + 64*STR;
  ushort* CS2 = CS3 + 64*STR;
  ushort* CS1 = CS2 + 16*STR;

  const int  tid = threadIdx.x;
  const int  b   = blockIdx.x;
  const long tokbase = (long)b * NTOK;
  const int  w    = tid >> 6;
  const int  lane = tid & 63;
  const int  n16  = lane & 15;
  const int  quad = lane >> 4;
  const int  mtg  = w >> 2, ntg = w & 3;
  const int  kof  = quad * 8;

  float bcv[2], bsv[2];
  #pragma unroll
  for (int j = 0; j < 2; j++) {
    const int c = ntg*32 + j*16 + n16;
    bcv[j] = Wcb[c]; bsv[j] = 4.f * Wsb[c];
  }

  short8 Bc[2][4];
  #pragma unroll
  for (int jt = 0; jt < 2; jt++)
    #pragma unroll
    for (int kb = 0; kb < 4; kb++) {
      const float* pc = WcW + (ntg*32 + jt*16 + n16)*ED + kb*32 + kof;
      Bc[jt][kb] = pack8(((const float4*)pc)[0], ((const float4*)pc)[1]);
    }

  #pragma unroll
  for (int i = 0; i < 8; i++) {
    const int idx = tid + i*512;
    float4 f = ((const float4*)WsW)[idx];
    *(ushort4*)(WsL + (idx >> 5)*STR + ((idx & 31) << 2)) = cvt4(f);
  }

  for (int i = tid; i < 1024; i += 512) PM[i] = 0.f;
  float pm[2] = {0.f, 0.f};

  float4 RA[4], RB[4];
  auto issue64 = [&](float4 (&R)[4], int ofs) {
    const int r = tid >> 3, p = tid & 7;
    const float4* src = (const float4*)(emb + (long)tokens[tokbase + ofs + r]*ED) + (p << 2);
    R[0] = src[0]; R[1] = src[1]; R[2] = src[2]; R[3] = src[3];
  };
  auto store64 = [&](const float4 (&R)[4], ushort* Xe) {
    const int r = tid >> 3, p = tid & 7;
    short8* d = (short8*)(Xe + r*STR + (p << 4));
    d[0] = pack8(R[0], R[1]); d[1] = pack8(R[2], R[3]);
  };
  auto issueN = [&](float4 (&R)[4], int ofs, int nrows) {
    const int r = tid >> 5, p = tid & 31;
    if (r < nrows) R[0] = ((const float4*)(emb + (long)tokens[tokbase + ofs + r]*ED))[p];
  };
  auto storeN = [&](const float4 (&R)[4], ushort* Xe, int nrows) {
    const int r = tid >> 5, p = tid & 31;
    if (r < nrows) *(ushort4*)(Xe + r*STR + (p << 2)) = cvt4(R[0]);
  };

  auto phase64 = [&](const ushort* Xe, const ushort* csrc, ushort* csdst, int csrow0) {
    f32x4 acc[2][2];
    #pragma unroll
    for (int i = 0; i < 2; i++)
      #pragma unroll
      for (int j = 0; j < 2; j++) acc[i][j] = (f32x4){0.f,0.f,0.f,0.f};
    #pragma unroll
    for (int kb = 0; kb < 4; kb++) {
      const int ko = kb*32 + kof;
      short8 a0 = *(const short8*)(Xe + (mtg*32      + n16)*STR + ko);
      short8 a1 = *(const short8*)(Xe + (mtg*32 + 16 + n16)*STR + ko);
      acc[0][0]=MFMA(a0,Bc[0][kb],acc[0][0]); acc[0][1]=MFMA(a0,Bc[1][kb],acc[0][1]);
      acc[1][0]=MFMA(a1,Bc[0][kb],acc[1][0]); acc[1][1]=MFMA(a1,Bc[1][kb],acc[1][1]);
      if (csrc) {
        short8 c0 = *(const short8*)(csrc + (mtg*32      + n16)*STR + ko);
        short8 c1 = *(const short8*)(csrc + (mtg*32 + 16 + n16)*STR + ko);
        short8 s0 = *(const short8*)(WsL  + (ntg*32      + n16)*STR + ko);
        short8 s1 = *(const short8*)(WsL  + (ntg*32 + 16 + n16)*STR + ko);
        acc[0][0]=MFMA(c0,s0,acc[0][0]); acc[0][1]=MFMA(c0,s1,acc[0][1]);
        acc[1][0]=MFMA(c1,s0,acc[1][0]); acc[1][1]=MFMA(c1,s1,acc[1][1]);
      }
    }
    #pragma unroll
    for (int i = 0; i < 2; i++) {
      const int p = mtg*8 + i*4 + quad;
      #pragma unroll
      for (int j = 0; j < 2; j++) {
        const float bb = csrc ? (bcv[j] + bsv[j]) : bcv[j];
        f32x4 A = acc[i][j];
        float h0=A[0]+bb, h1=A[1]+bb, h2=A[2]+bb, h3=A[3]+bb;
        pm[j] = fmaxf(pm[j], fmaxf(fmaxf(h0,h1), fmaxf(h2,h3)));
        csdst[(csrow0 + p)*STR + ntg*32 + j*16 + n16] =
            f2bf(A[0]+A[1]+A[2]+A[3] + 4.f*bb);
      }
    }
  };

  auto smallphase = [&](const ushort* Xe, const ushort* csrc, int M, ushort* csdst) {
    if (mtg != 0) return;
    const int ar = (M == 16) ? n16 : ((M == 4) ? (n16 & 3) : 0);
    f32x4 acc[2];
    acc[0] = (f32x4){0.f,0.f,0.f,0.f}; acc[1] = (f32x4){0.f,0.f,0.f,0.f};
    #pragma unroll
    for (int kb = 0; kb < 4; kb++) {
      const int ko = kb*32 + kof;
      short8 a  = *(const short8*)(Xe   + ar*STR + ko);
      short8 c2 = *(const short8*)(csrc + ar*STR + ko);
      short8 s0 = *(const short8*)(WsL + (ntg*32      + n16)*STR + ko);
      short8 s1 = *(const short8*)(WsL + (ntg*32 + 16 + n16)*STR + ko);
      acc[0] = MFMA(a,  Bc[0][kb], acc[0]); acc[1] = MFMA(a,  Bc[1][kb], acc[1]);
      acc[0] = MFMA(c2, s0, acc[0]);        acc[1] = MFMA(c2, s1, acc[1]);
    }
    #pragma unroll
    for (int j = 0; j < 2; j++) {
      const float bb = bcv[j] + bsv[j];
      f32x4 A = acc[j];
      const int c = ntg*32 + j*16 + n16;
      if (M == 16) {
        float h0=A[0]+bb, h1=A[1]+bb, h2=A[2]+bb, h3=A[3]+bb;
        pm[j] = fmaxf(pm[j], fmaxf(fmaxf(h0,h1), fmaxf(h2,h3)));
        csdst[quad*STR + c] = f2bf(A[0]+A[1]+A[2]+A[3] + 4.f*bb);
      } else if (M == 4) {
        if (quad == 0) {
          float h0=A[0]+bb, h1=A[1]+bb, h2=A[2]+bb, h3=A[3]+bb;
          pm[j] = fmaxf(pm[j], fmaxf(fmaxf(h0,h1), fmaxf(h2,h3)));
          csdst[c] = f2bf(A[0]+A[1]+A[2]+A[3] + 4.f*bb);
        }
      } else {
        if (quad == 0) pm[j] = fmaxf(pm[j], A[0] + bb);
      }
    }
  };

  issue64(RA, 341);
  issue64(RB, 341 + 64);
  store64(RA, Xe0);
  __syncthreads();
  issue64(RA, 341+128);     phase64(Xe0, nullptr, CS4,  0); store64(RB, Xe1); __syncthreads();
  issue64(RB, 341+192);     phase64(Xe1, nullptr, CS4, 16); store64(RA, Xe0); __syncthreads();
  issue64(RA, 85);          phase64(Xe0, nullptr, CS4, 32); store64(RB, Xe1); __syncthreads();
  issue64(RB, 341+256);     phase64(Xe1, nullptr, CS4, 48); store64(RA, Xe0); __syncthreads();
  issue64(RA, 341+256+64);  phase64(Xe0, CS4,     CS3,  0); store64(RB, Xe1); __syncthreads();
  issue64(RB, 341+256+128); phase64(Xe1, nullptr, CS4,  0); store64(RA, Xe0); __syncthreads();
  issue64(RA, 341+256+192); phase64(Xe0, nullptr, CS4, 16); store64(RB, Xe1); __syncthreads();
  issue64(RB, 85+64);       phase64(Xe1, nullptr, CS4, 32); store64(RA, Xe0); __syncthreads();
  issue64(RA, 341+512);     phase64(Xe0, nullptr, CS4, 48); store64(RB, Xe1); __syncthreads();
  issue64(RB, 341+512+64);  phase64(Xe1, CS4,     CS3, 16); store64(RA, Xe0); __syncthreads();
  issue64(RA, 341+512+128); phase64(Xe0, nullptr, CS4,  0); store64(RB, Xe1); __syncthreads();
  issue64(RB, 341+512+192); phase64(Xe1, nullptr, CS4, 16); store64(RA, Xe0); __syncthreads();
  issue64(RA, 85+128);      phase64(Xe0, nullptr, CS4, 32); store64(RB, Xe1); __syncthreads();
  issue64(RB, 341+768);     phase64(Xe1, nullptr, CS4, 48); store64(RA, Xe0); __syncthreads();
  issue64(RA, 341+768+64);  phase64(Xe0, CS4,     CS3, 32); store64(RB, Xe1); __syncthreads();
  issue64(RB, 341+768+128); phase64(Xe1, nullptr, CS4,  0); store64(RA, Xe0); __syncthreads();
  issue64(RA, 341+768+192); phase64(Xe0, nullptr, CS4, 16); store64(RB, Xe1); __syncthreads();
  issue64(RB, 85+192);      phase64(Xe1, nullptr, CS4, 32); store64(RA, Xe0); __syncthreads();
  issue64(RA, 21);          phase64(Xe0, nullptr, CS4, 48); store64(RB, Xe1); __syncthreads();
  issueN(RB, 5, 16);        phase64(Xe1, CS4,     CS3, 48); store64(RA, Xe0); __syncthreads();
  issueN(RA, 1, 4);         phase64(Xe0, CS3,     CS2,  0); storeN(RB, Xe1, 16); __syncthreads();
  issueN(RB, 0, 1);         smallphase(Xe1, CS2, 16, CS1);  storeN(RA, Xe0, 4);  __syncthreads();
                            smallphase(Xe0, CS1, 4,  CS2);  storeN(RB, Xe1, 1);  __syncthreads();
                            smallphase(Xe1, CS2, 1,  nullptr);

  #pragma unroll
  for (int j = 0; j < 2; j++) {
    float v = pm[j];
    v = fmaxf(v, __shfl_xor(v, 16, 64));
    v = fmaxf(v, __shfl_xor(v, 32, 64));
    if (quad == 0) PM[w*128 + ntg*32 + j*16 + n16] = v;
  }
  __syncthreads();
  if (tid < 128) {
    float m = 0.f;
    #pragma unroll
    for (int r = 0; r < 8; r++) m = fmaxf(m, PM[r*128 + tid]);
    out[(long)b*ED + tid] = m;
  }
}

extern "C" void kernel_launch(void* const* d_in, const int* in_sizes, int n_in,
                              void* d_out, int out_size, void* d_ws, size_t ws_size,
                              hipStream_t stream) {
  const int*   tokens = (const int*)d_in[0];
  const float* emb    = (const float*)d_in[1];
  const float* WcW    = (const float*)d_in[2];
  const float* Wcb    = (const float*)d_in[3];
  const float* WsW    = (const float*)d_in[4];
  const float* Wsb    = (const float*)d_in[5];
  float* out = (float*)d_out;

  const size_t needP = (size_t)PROWS * ED * sizeof(ushort);
  if (d_ws != nullptr && ws_size >= needP) {
    ushort* P = (ushort*)d_ws;
    proj_kernel<<<(VROWS + 63) / 64, 256, 0, stream>>>(emb, WcW, Wcb, P);
    hipFuncSetAttribute(reinterpret_cast<const void*>(tree_kernel_p),
                        hipFuncAttributeMaxDynamicSharedMemorySize, SMP_BYTES);
    tree_kernel_p<<<512, 512, SMP_BYTES, stream>>>(tokens, P, WsW, Wsb, out);
  } else {
    hipFuncSetAttribute(reinterpret_cast<const void*>(tree_kernel),
                        hipFuncAttributeMaxDynamicSharedMemorySize, SM_BYTES);
    tree_kernel<<<512, 512, SM_BYTES, stream>>>(tokens, emb, WcW, Wcb, WsW, Wsb, out);
  }
}